// Round 2
// 675.452 us; speedup vs baseline: 1.0100x; 1.0100x over previous
//
#include <hip/hip_runtime.h>
#include <math.h>

#define H 1024
#define V 50257
#define S 4096

// d_out layout (floats): [0,V) log_softmax, [V,V+H) h_new, [V+H,V+2H) c_new, [V+2H,V+2H+S) attn_w
#define OUT_H (V)
#define OUT_C (V + H)
#define OUT_A (V + 2 * H)

// ws layout (floats). WS_V padded to 16B alignment for float4 reads.
#define WS_LOGITS 0
#define WS_V      50260            // V rounded up to multiple of 4
#define WS_CTX    (WS_V + H)       // 51284
#define WS_SCORES (WS_CTX + H)     // 52308
#define WS_SB     (WS_SCORES + S)  // 56404
#define WS_PM     (WS_SB + 4)      // 56408 (32 floats)
#define WS_PL     (WS_PM + 32)     // 56440 (32 floats)
#define WS_H      (WS_PL + 32)     // 56472 — 16B-aligned mirror of h_new for float4 GEMV loads

// Piggyback GEMV row partition (16 rows per 256-thread block, 4 waves x 4 rows)
#define GEMV_A_BLOCKS 938          // attnv:   rows [0, 15008)
#define GEMV_S_BLOCKS 938          // scores:  rows [15008, 30016)
#define GEMV_C_BLOCKS 1266         // context: rows [30016, 50272) ∩ [0,V)
#define GEMV_S_BASE 15008
#define GEMV_C_BASE 30016

__device__ __forceinline__ float wave_red(float v) {
#pragma unroll
    for (int off = 32; off > 0; off >>= 1) v += __shfl_xor(v, off, 64);
    return v;
}

// h-half of the logits GEMV: ws[WS_LOGITS+r] = out_W[r, 0:1024]·h + out_b[r]
// One 256-thread block covers 16 rows. h chunk register-cached per wave.
__device__ __forceinline__ void gemv_h_block(
    const float* __restrict__ outW, const float* __restrict__ outb,
    const float* __restrict__ h, float* __restrict__ ws, int base, int t)
{
    int wave = t >> 6, lane = t & 63;
    const float4* h4 = (const float4*)h;
    float4 hv0 = h4[lane], hv1 = h4[lane + 64], hv2 = h4[lane + 128], hv3 = h4[lane + 192];
    int r0 = base + wave * 4;
#pragma unroll
    for (int i = 0; i < 4; i++) {
        int r = r0 + i;
        if (r < V) {
            const float4* w4 = (const float4*)(outW + (size_t)r * 2048);
            float4 a = w4[lane];
            float acc = a.x * hv0.x + a.y * hv0.y + a.z * hv0.z + a.w * hv0.w;
            a = w4[lane + 64];  acc += a.x * hv1.x + a.y * hv1.y + a.z * hv1.z + a.w * hv1.w;
            a = w4[lane + 128]; acc += a.x * hv2.x + a.y * hv2.y + a.z * hv2.z + a.w * hv2.w;
            a = w4[lane + 192]; acc += a.x * hv3.x + a.y * hv3.y + a.z * hv3.z + a.w * hv3.w;
            acc = wave_red(acc);
            if (lane == 0) ws[WS_LOGITS + r] = acc + outb[r];
        }
    }
}

// ---------------- K1: LSTM cell. Wave-per-gate-row shuffle reduce. Aux blocks zero atomic targets. ----------------
__global__ __launch_bounds__(256) void lstm_kernel(
    const int* __restrict__ word, const float* __restrict__ emb,
    const float* __restrict__ Wih, const float* __restrict__ Whh,
    const float* __restrict__ bih, const float* __restrict__ bhh,
    const float* __restrict__ h0, const float* __restrict__ c0,
    float* __restrict__ out, float* __restrict__ ws)
{
    int b = blockIdx.x, t = threadIdx.x;
    if (b >= H) {
        int z = b - H;
        if (z < 4)      ws[WS_V + z * 256 + t] = 0.f;
        else if (z < 8) ws[WS_CTX + (z - 4) * 256 + t] = 0.f;
        else if (t == 0) ws[WS_SB] = 0.f;
        return;
    }
    int wave = t >> 6, lane = t & 63;
    int row = b + wave * H;                       // wave r handles gate r for hidden index b
    const float4* x4 = (const float4*)(emb + (size_t)word[0] * H);
    const float4* h4 = (const float4*)h0;
    const float4* wi = (const float4*)(Wih + (size_t)row * H);
    const float4* wh = (const float4*)(Whh + (size_t)row * H);
    float acc = 0.f;
#pragma unroll
    for (int k = 0; k < 4; k++) {
        int idx = lane + 64 * k;
        float4 a = wi[idx], xb = x4[idx];
        acc += a.x * xb.x + a.y * xb.y + a.z * xb.z + a.w * xb.w;
        float4 c = wh[idx], hb = h4[idx];
        acc += c.x * hb.x + c.y * hb.y + c.z * hb.z + c.w * hb.w;
    }
    acc = wave_red(acc);
    __shared__ float gates[4];
    if (lane == 0) gates[wave] = acc;
    __syncthreads();
    if (t == 0) {
        int j = b;
        float ig = gates[0] + bih[j]         + bhh[j];
        float fg = gates[1] + bih[j + H]     + bhh[j + H];
        float gg = gates[2] + bih[j + 2 * H] + bhh[j + 2 * H];
        float og = gates[3] + bih[j + 3 * H] + bhh[j + 3 * H];
        float si = 1.f / (1.f + expf(-ig));
        float sf = 1.f / (1.f + expf(-fg));
        float so = 1.f / (1.f + expf(-og));
        float cn = sf * c0[j] + si * tanhf(gg);
        float hn = so * tanhf(cn);
        out[OUT_C + j] = cn;
        out[OUT_H + j] = hn;
        ws[WS_H + j]   = hn;   // aligned mirror for float4 GEMV loads
    }
}

// ---------------- K2: v[k] = sum_j h[j]*attn_W[j,k] (+ sb partials) + piggyback h-GEMV ----------------
__global__ __launch_bounds__(256) void attnv_kernel(
    const float* __restrict__ attn_W, const float* __restrict__ attn_b,
    const float* __restrict__ out, const float* __restrict__ outW,
    const float* __restrict__ outb, float* ws)
{
    int b = blockIdx.x, t = threadIdx.x;
    if (b < 128) {
        int jb = b & 31, kb = b >> 5;             // jb: 32-j slice, kb: 256-k slice
        __shared__ float hs[32];
        if (t < 32) hs[t] = out[OUT_H + jb * 32 + t];
        __syncthreads();
        float acc = 0.f;
        const float* base = attn_W + (size_t)(jb * 32) * H + kb * 256 + t;
#pragma unroll 8
        for (int jj = 0; jj < 32; jj++) acc += hs[jj] * base[(size_t)jj * H];
        atomicAdd(&ws[WS_V + kb * 256 + t], acc);
        if (kb == 0 && t < 32) {                  // sb = attn_b·h, partial per jb slice
            float p = hs[t] * attn_b[jb * 32 + t];
#pragma unroll
            for (int off = 16; off > 0; off >>= 1) p += __shfl_xor(p, off, 32);
            if (t == 0) atomicAdd(&ws[WS_SB], p);
        }
    } else {
        gemv_h_block(outW, outb, ws + WS_H, ws, (b - 128) * 16, t);
    }
}

// ---------------- K3: scores[s] = enc[s]·v + sb + piggyback h-GEMV ----------------
__global__ __launch_bounds__(256) void scores_kernel(
    const float* __restrict__ enc, const float* __restrict__ outW,
    const float* __restrict__ outb, float* ws)
{
    int b = blockIdx.x, t = threadIdx.x;
    int wave = t >> 6, lane = t & 63;
    if (b < S / 4) {
        int s = b * 4 + wave;
        const float4* e4 = (const float4*)(enc + (size_t)s * H);
        const float4* v4 = (const float4*)(ws + WS_V);
        float acc = 0.f;
#pragma unroll
        for (int it = 0; it < 4; it++) {
            float4 a = e4[lane + 64 * it];
            float4 bb = v4[lane + 64 * it];
            acc += a.x * bb.x + a.y * bb.y + a.z * bb.z + a.w * bb.w;
        }
        acc = wave_red(acc);
        if (lane == 0) ws[WS_SCORES + s] = acc + ws[WS_SB];
    } else {
        gemv_h_block(outW, outb, ws + WS_H, ws, GEMV_S_BASE + (b - S / 4) * 16, t);
    }
}

// ---------------- K4: softmax over S=4096 scores, one block (latency-critical, no piggyback) ----------------
__global__ __launch_bounds__(1024) void softmax_kernel(
    const float* __restrict__ ws, float* __restrict__ out)
{
    int t = threadIdx.x;
    float x[4];
    float m = -INFINITY;
#pragma unroll
    for (int i = 0; i < 4; i++) { x[i] = ws[WS_SCORES + t + i * 1024]; m = fmaxf(m, x[i]); }
    __shared__ float red[1024];
    __shared__ float sm, sl;
    red[t] = m; __syncthreads();
    for (int off = 512; off > 0; off >>= 1) { if (t < off) red[t] = fmaxf(red[t], red[t + off]); __syncthreads(); }
    if (t == 0) sm = red[0];
    __syncthreads();
    m = sm;
    float l = 0.f;
#pragma unroll
    for (int i = 0; i < 4; i++) { x[i] = expf(x[i] - m); l += x[i]; }
    red[t] = l; __syncthreads();
    for (int off = 512; off > 0; off >>= 1) { if (t < off) red[t] += red[t + off]; __syncthreads(); }
    if (t == 0) sl = red[0];
    __syncthreads();
    float inv = 1.f / sl;
#pragma unroll
    for (int i = 0; i < 4; i++) out[OUT_A + t + i * 1024] = x[i] * inv;
}

// ---------------- K5: context[k] = sum_s attn_w[s]*enc[s,k] + piggyback h-GEMV ----------------
__global__ __launch_bounds__(256) void context_kernel(
    const float* __restrict__ enc, const float* __restrict__ out,
    const float* __restrict__ outW, const float* __restrict__ outb, float* ws)
{
    int b = blockIdx.x, t = threadIdx.x;
    if (b < 256) {
        int sb = b >> 2, kb = b & 3;              // sb: 64-s slice, kb: 256-k slice
        const float* aw = out + OUT_A;
        float acc = 0.f;
        for (int ss = 0; ss < 64; ss++) {
            int s = sb * 64 + ss;
            acc += aw[s] * enc[(size_t)s * H + kb * 256 + t];
        }
        atomicAdd(&ws[WS_CTX + kb * 256 + t], acc);
    } else {
        gemv_h_block(outW, outb, ws + WS_H, ws, GEMV_C_BASE + (b - 256) * 16, t);
    }
}

// ---------------- K6: ctx-half of logits: ws[r] += out_W[r,1024:2048]·ctx ----------------
__global__ __launch_bounds__(256) void logits_ctx_kernel(
    const float* __restrict__ outW, float* ws)
{
    int t = threadIdx.x;
    int wave = t >> 6, lane = t & 63;
    const float4* c4 = (const float4*)(ws + WS_CTX);
    float4 cv0 = c4[lane], cv1 = c4[lane + 64], cv2 = c4[lane + 128], cv3 = c4[lane + 192];
    int r0 = blockIdx.x * 16 + wave * 4;
#pragma unroll
    for (int i = 0; i < 4; i++) {
        int r = r0 + i;
        if (r < V) {
            const float4* w4 = (const float4*)(outW + (size_t)r * 2048 + 1024);
            float4 a = w4[lane];
            float acc = a.x * cv0.x + a.y * cv0.y + a.z * cv0.z + a.w * cv0.w;
            a = w4[lane + 64];  acc += a.x * cv1.x + a.y * cv1.y + a.z * cv1.z + a.w * cv1.w;
            a = w4[lane + 128]; acc += a.x * cv2.x + a.y * cv2.y + a.z * cv2.z + a.w * cv2.w;
            a = w4[lane + 192]; acc += a.x * cv3.x + a.y * cv3.y + a.z * cv3.z + a.w * cv3.w;
            acc = wave_red(acc);
            if (lane == 0) ws[WS_LOGITS + r] += acc;   // h-half + out_b already there
        }
    }
}

// ---------------- K7: 32-block online (m, sumexp) partials over logits ----------------
__global__ __launch_bounds__(256) void lse_partial_kernel(float* ws)
{
    int t = threadIdx.x, b = blockIdx.x;
    float m = -INFINITY, l = 0.f;
    for (int i = b * 256 + t; i < V; i += 32 * 256) {
        float x = ws[WS_LOGITS + i];
        float nm = fmaxf(m, x);
        l = l * expf(m - nm) + expf(x - nm);
        m = nm;
    }
    __shared__ float sm[256], sl[256];
    sm[t] = m; sl[t] = l; __syncthreads();
    for (int off = 128; off > 0; off >>= 1) {
        if (t < off) {
            float m2 = sm[t + off], l2 = sl[t + off];
            float nm = fmaxf(sm[t], m2);
            sl[t] = sl[t] * expf(sm[t] - nm) + l2 * expf(m2 - nm);
            sm[t] = nm;
        }
        __syncthreads();
    }
    if (t == 0) { ws[WS_PM + b] = sm[0]; ws[WS_PL + b] = sl[0]; }
}

// ---------------- K8: combine partials, write log_softmax ----------------
__global__ __launch_bounds__(256) void lsout_kernel(const float* __restrict__ ws, float* __restrict__ out)
{
    __shared__ float fm, fl;
    int t = threadIdx.x;
    if (t == 0) {
        float m = -INFINITY, l = 0.f;
        for (int p = 0; p < 32; p++) {
            float m2 = ws[WS_PM + p], l2 = ws[WS_PL + p];
            float nm = fmaxf(m, m2);
            l = l * expf(m - nm) + l2 * expf(m2 - nm);
            m = nm;
        }
        fm = m; fl = logf(l);
    }
    __syncthreads();
    int i = blockIdx.x * 256 + t;
    if (i < V) out[i] = ws[WS_LOGITS + i] - fm - fl;
}

extern "C" void kernel_launch(void* const* d_in, const int* in_sizes, int n_in,
                              void* d_out, int out_size, void* d_ws, size_t ws_size,
                              hipStream_t stream) {
    const int*   word   = (const int*)d_in[0];
    const float* h0     = (const float*)d_in[1];
    const float* c0     = (const float*)d_in[2];
    const float* enc    = (const float*)d_in[3];
    const float* emb    = (const float*)d_in[4];
    const float* Wih    = (const float*)d_in[5];
    const float* Whh    = (const float*)d_in[6];
    const float* bih    = (const float*)d_in[7];
    const float* bhh    = (const float*)d_in[8];
    const float* attn_W = (const float*)d_in[9];
    const float* attn_b = (const float*)d_in[10];
    const float* outW   = (const float*)d_in[11];
    const float* outb   = (const float*)d_in[12];
    float* out = (float*)d_out;
    float* ws  = (float*)d_ws;

    lstm_kernel<<<H + 9, 256, 0, stream>>>(word, emb, Wih, Whh, bih, bhh, h0, c0, out, ws);
    attnv_kernel<<<128 + GEMV_A_BLOCKS, 256, 0, stream>>>(attn_W, attn_b, out, outW, outb, ws);
    scores_kernel<<<S / 4 + GEMV_S_BLOCKS, 256, 0, stream>>>(enc, outW, outb, ws);
    softmax_kernel<<<1, 1024, 0, stream>>>(ws, out);
    context_kernel<<<256 + GEMV_C_BLOCKS, 256, 0, stream>>>(enc, out, outW, outb, ws);
    logits_ctx_kernel<<<(V + 15) / 16, 256, 0, stream>>>(outW, ws);
    lse_partial_kernel<<<32, 256, 0, stream>>>(ws);
    lsout_kernel<<<(V + 255) / 256, 256, 0, stream>>>(ws, out);
}

// Round 3
// 670.626 us; speedup vs baseline: 1.0173x; 1.0072x over previous
//
#include <hip/hip_runtime.h>
#include <math.h>

#define H 1024
#define V 50257
#define S 4096

// d_out layout (floats): [0,V) log_softmax, [V,V+H) h_new, [V+H,V+2H) c_new, [V+2H,V+2H+S) attn_w
#define OUT_H (V)
#define OUT_C (V + H)
#define OUT_A (V + 2 * H)

// ws layout (floats). WS_V padded to 16B alignment for float4 reads.
#define WS_LOGITS 0
#define WS_V      50260            // V rounded up to multiple of 4
#define WS_CTX    (WS_V + H)       // 51284
#define WS_SCORES (WS_CTX + H)     // 52308
#define WS_SB     (WS_SCORES + S)  // 56404
#define WS_PM     (WS_SB + 4)      // 56408 (LCB floats: per-block online max)
#define WS_PL     (WS_PM + 3144)   // 59552 (LCB floats: per-block online sumexp)
#define WS_H      (WS_PL + 3144)   // 62696 — byte 250784, 16B-aligned mirror of h_new

#define LCB 3142                   // logits_ctx blocks = ceil(V/16)

// Piggyback GEMV row partition. 16 rows per 256-thread block (4 waves x 4 rows);
// softmax blocks are 1024 threads -> 64 rows per block.
#define GEMV_A_BLOCKS 900          // attnv:   rows [0, 14400)
#define GEMV_S_BLOCKS 900          // scores:  rows [14400, 28800)
#define GEMV_SM_BLOCKS 96          // softmax: rows [28800, 34944) (64 rows/block)
#define GEMV_C_BLOCKS 958          // context: rows [34944, 50272) ∩ [0,V)
#define GEMV_S_BASE  14400
#define GEMV_SM_BASE 28800
#define GEMV_C_BASE  34944

__device__ __forceinline__ float wave_red(float v) {
#pragma unroll
    for (int off = 32; off > 0; off >>= 1) v += __shfl_xor(v, off, 64);
    return v;
}

// h-half of the logits GEMV: ws[WS_LOGITS+r] = out_W[r, 0:1024]·h + out_b[r]
// Each wave covers 4 rows; works for any blockDim multiple of 64.
__device__ __forceinline__ void gemv_h_block(
    const float* __restrict__ outW, const float* __restrict__ outb,
    const float* __restrict__ h, float* __restrict__ ws, int base, int t)
{
    int wave = t >> 6, lane = t & 63;
    const float4* h4 = (const float4*)h;
    float4 hv0 = h4[lane], hv1 = h4[lane + 64], hv2 = h4[lane + 128], hv3 = h4[lane + 192];
    int r0 = base + wave * 4;
#pragma unroll
    for (int i = 0; i < 4; i++) {
        int r = r0 + i;
        if (r < V) {
            const float4* w4 = (const float4*)(outW + (size_t)r * 2048);
            float4 a = w4[lane];
            float acc = a.x * hv0.x + a.y * hv0.y + a.z * hv0.z + a.w * hv0.w;
            a = w4[lane + 64];  acc += a.x * hv1.x + a.y * hv1.y + a.z * hv1.z + a.w * hv1.w;
            a = w4[lane + 128]; acc += a.x * hv2.x + a.y * hv2.y + a.z * hv2.z + a.w * hv2.w;
            a = w4[lane + 192]; acc += a.x * hv3.x + a.y * hv3.y + a.z * hv3.z + a.w * hv3.w;
            acc = wave_red(acc);
            if (lane == 0) ws[WS_LOGITS + r] = acc + outb[r];
        }
    }
}

// ---------------- K1: LSTM cell. Wave-per-gate-row shuffle reduce. Aux blocks zero atomic targets. ----------------
__global__ __launch_bounds__(256) void lstm_kernel(
    const int* __restrict__ word, const float* __restrict__ emb,
    const float* __restrict__ Wih, const float* __restrict__ Whh,
    const float* __restrict__ bih, const float* __restrict__ bhh,
    const float* __restrict__ h0, const float* __restrict__ c0,
    float* __restrict__ out, float* __restrict__ ws)
{
    int b = blockIdx.x, t = threadIdx.x;
    if (b >= H) {
        int z = b - H;
        if (z < 4)      ws[WS_V + z * 256 + t] = 0.f;
        else if (z < 8) ws[WS_CTX + (z - 4) * 256 + t] = 0.f;
        else if (t == 0) ws[WS_SB] = 0.f;
        return;
    }
    int wave = t >> 6, lane = t & 63;
    int row = b + wave * H;                       // wave r handles gate r for hidden index b
    const float4* x4 = (const float4*)(emb + (size_t)word[0] * H);
    const float4* h4 = (const float4*)h0;
    const float4* wi = (const float4*)(Wih + (size_t)row * H);
    const float4* wh = (const float4*)(Whh + (size_t)row * H);
    float acc = 0.f;
#pragma unroll
    for (int k = 0; k < 4; k++) {
        int idx = lane + 64 * k;
        float4 a = wi[idx], xb = x4[idx];
        acc += a.x * xb.x + a.y * xb.y + a.z * xb.z + a.w * xb.w;
        float4 c = wh[idx], hb = h4[idx];
        acc += c.x * hb.x + c.y * hb.y + c.z * hb.z + c.w * hb.w;
    }
    acc = wave_red(acc);
    __shared__ float gates[4];
    if (lane == 0) gates[wave] = acc;
    __syncthreads();
    if (t == 0) {
        int j = b;
        float ig = gates[0] + bih[j]         + bhh[j];
        float fg = gates[1] + bih[j + H]     + bhh[j + H];
        float gg = gates[2] + bih[j + 2 * H] + bhh[j + 2 * H];
        float og = gates[3] + bih[j + 3 * H] + bhh[j + 3 * H];
        float si = 1.f / (1.f + expf(-ig));
        float sf = 1.f / (1.f + expf(-fg));
        float so = 1.f / (1.f + expf(-og));
        float cn = sf * c0[j] + si * tanhf(gg);
        float hn = so * tanhf(cn);
        out[OUT_C + j] = cn;
        out[OUT_H + j] = hn;
        ws[WS_H + j]   = hn;   // aligned mirror for float4 GEMV loads
    }
}

// ---------------- K2: v[k] = sum_j h[j]*attn_W[j,k] (+ sb partials) + piggyback h-GEMV ----------------
__global__ __launch_bounds__(256) void attnv_kernel(
    const float* __restrict__ attn_W, const float* __restrict__ attn_b,
    const float* __restrict__ out, const float* __restrict__ outW,
    const float* __restrict__ outb, float* ws)
{
    int b = blockIdx.x, t = threadIdx.x;
    if (b < 128) {
        int jb = b & 31, kb = b >> 5;             // jb: 32-j slice, kb: 256-k slice
        __shared__ float hs[32];
        if (t < 32) hs[t] = out[OUT_H + jb * 32 + t];
        __syncthreads();
        float acc = 0.f;
        const float* base = attn_W + (size_t)(jb * 32) * H + kb * 256 + t;
#pragma unroll 8
        for (int jj = 0; jj < 32; jj++) acc += hs[jj] * base[(size_t)jj * H];
        atomicAdd(&ws[WS_V + kb * 256 + t], acc);
        if (kb == 0 && t < 32) {                  // sb = attn_b·h, partial per jb slice
            float p = hs[t] * attn_b[jb * 32 + t];
#pragma unroll
            for (int off = 16; off > 0; off >>= 1) p += __shfl_xor(p, off, 32);
            if (t == 0) atomicAdd(&ws[WS_SB], p);
        }
    } else {
        gemv_h_block(outW, outb, ws + WS_H, ws, (b - 128) * 16, t);
    }
}

// ---------------- K3: scores[s] = enc[s]·v + sb + piggyback h-GEMV ----------------
__global__ __launch_bounds__(256) void scores_kernel(
    const float* __restrict__ enc, const float* __restrict__ outW,
    const float* __restrict__ outb, float* ws)
{
    int b = blockIdx.x, t = threadIdx.x;
    int wave = t >> 6, lane = t & 63;
    if (b < S / 4) {
        int s = b * 4 + wave;
        const float4* e4 = (const float4*)(enc + (size_t)s * H);
        const float4* v4 = (const float4*)(ws + WS_V);
        float acc = 0.f;
#pragma unroll
        for (int it = 0; it < 4; it++) {
            float4 a = e4[lane + 64 * it];
            float4 bb = v4[lane + 64 * it];
            acc += a.x * bb.x + a.y * bb.y + a.z * bb.z + a.w * bb.w;
        }
        acc = wave_red(acc);
        if (lane == 0) ws[WS_SCORES + s] = acc + ws[WS_SB];
    } else {
        gemv_h_block(outW, outb, ws + WS_H, ws, GEMV_S_BASE + (b - S / 4) * 16, t);
    }
}

// ---------------- K4: softmax over S=4096 scores (block 0) + piggyback h-GEMV (blocks 1..96) ----------------
__global__ __launch_bounds__(1024) void softmax_kernel(
    const float* __restrict__ ws_c, float* __restrict__ out,
    const float* __restrict__ outW, const float* __restrict__ outb, float* ws)
{
    int t = threadIdx.x;
    if (blockIdx.x > 0) {
        // 16 waves x 4 rows = 64 rows per block
        gemv_h_block(outW, outb, ws + WS_H, ws, GEMV_SM_BASE + (blockIdx.x - 1) * 64, t);
        return;
    }
    float x[4];
    float m = -INFINITY;
#pragma unroll
    for (int i = 0; i < 4; i++) { x[i] = ws_c[WS_SCORES + t + i * 1024]; m = fmaxf(m, x[i]); }
    __shared__ float red[1024];
    __shared__ float sm, sl;
    red[t] = m; __syncthreads();
    for (int off = 512; off > 0; off >>= 1) { if (t < off) red[t] = fmaxf(red[t], red[t + off]); __syncthreads(); }
    if (t == 0) sm = red[0];
    __syncthreads();
    m = sm;
    float l = 0.f;
#pragma unroll
    for (int i = 0; i < 4; i++) { x[i] = expf(x[i] - m); l += x[i]; }
    red[t] = l; __syncthreads();
    for (int off = 512; off > 0; off >>= 1) { if (t < off) red[t] += red[t + off]; __syncthreads(); }
    if (t == 0) sl = red[0];
    __syncthreads();
    float inv = 1.f / sl;
#pragma unroll
    for (int i = 0; i < 4; i++) out[OUT_A + t + i * 1024] = x[i] * inv;
}

// ---------------- K5: context[k] = sum_s attn_w[s]*enc[s,k] + piggyback h-GEMV ----------------
__global__ __launch_bounds__(256) void context_kernel(
    const float* __restrict__ enc, const float* __restrict__ out,
    const float* __restrict__ outW, const float* __restrict__ outb, float* ws)
{
    int b = blockIdx.x, t = threadIdx.x;
    if (b < 256) {
        int sb = b >> 2, kb = b & 3;              // sb: 64-s slice, kb: 256-k slice
        const float* aw = out + OUT_A;
        float acc = 0.f;
        for (int ss = 0; ss < 64; ss++) {
            int s = sb * 64 + ss;
            acc += aw[s] * enc[(size_t)s * H + kb * 256 + t];
        }
        atomicAdd(&ws[WS_CTX + kb * 256 + t], acc);
    } else {
        gemv_h_block(outW, outb, ws + WS_H, ws, GEMV_C_BASE + (b - 256) * 16, t);
    }
}

// ---------------- K6: ctx-half of logits + fused per-block online (m,l) partial ----------------
__global__ __launch_bounds__(256) void logits_ctx_kernel(
    const float* __restrict__ outW, float* ws)
{
    int t = threadIdx.x;
    int wave = t >> 6, lane = t & 63;
    const float4* c4 = (const float4*)(ws + WS_CTX);
    float4 cv0 = c4[lane], cv1 = c4[lane + 64], cv2 = c4[lane + 128], cv3 = c4[lane + 192];
    int r0 = blockIdx.x * 16 + wave * 4;
    float pm = -INFINITY, pl = 0.f;
#pragma unroll
    for (int i = 0; i < 4; i++) {
        int r = r0 + i;
        if (r < V) {
            const float4* w4 = (const float4*)(outW + (size_t)r * 2048 + 1024);
            float4 a = w4[lane];
            float acc = a.x * cv0.x + a.y * cv0.y + a.z * cv0.z + a.w * cv0.w;
            a = w4[lane + 64];  acc += a.x * cv1.x + a.y * cv1.y + a.z * cv1.z + a.w * cv1.w;
            a = w4[lane + 128]; acc += a.x * cv2.x + a.y * cv2.y + a.z * cv2.z + a.w * cv2.w;
            a = w4[lane + 192]; acc += a.x * cv3.x + a.y * cv3.y + a.z * cv3.z + a.w * cv3.w;
            acc = wave_red(acc);
            if (lane == 0) {
                float fin = ws[WS_LOGITS + r] + acc;   // h-half + out_b already there
                ws[WS_LOGITS + r] = fin;
                float nm = fmaxf(pm, fin);             // fin finite; pm=-INF safe (exp(-INF)=0, pl=0)
                pl = pl * expf(pm - nm) + expf(fin - nm);
                pm = nm;
            }
        }
    }
    __shared__ float sm4[4], sl4[4];
    if (lane == 0) { sm4[wave] = pm; sl4[wave] = pl; }
    __syncthreads();
    if (t == 0) {
        float m = sm4[0], l = sl4[0];
#pragma unroll
        for (int w = 1; w < 4; w++) {
            float m2 = sm4[w], l2 = sl4[w];
            float nm = fmaxf(m, m2);
            if (nm > -INFINITY) {                      // guard both-empty (exp(NaN))
                l = l * expf(m - nm) + l2 * expf(m2 - nm);
                m = nm;
            }
        }
        ws[WS_PM + blockIdx.x] = m;
        ws[WS_PL + blockIdx.x] = l;
    }
}

// ---------------- K7: reduce LCB partials, write log_softmax ----------------
__global__ __launch_bounds__(256) void lsout_kernel(const float* __restrict__ ws, float* __restrict__ out)
{
    int t = threadIdx.x;
    float m = -INFINITY, l = 0.f;
    for (int i = t; i < LCB; i += 256) {              // every thread gets >=1 partial (LCB > 256)
        float m2 = ws[WS_PM + i], l2 = ws[WS_PL + i];
        float nm = fmaxf(m, m2);
        l = l * expf(m - nm) + l2 * expf(m2 - nm);    // first iter: l=0, exp(-INF)=0 -> l=l2
        m = nm;
    }
    __shared__ float sm[256], sl[256];
    __shared__ float fm, fl;
    sm[t] = m; sl[t] = l; __syncthreads();
    for (int off = 128; off > 0; off >>= 1) {
        if (t < off) {
            float m2 = sm[t + off], l2 = sl[t + off];
            float nm = fmaxf(sm[t], m2);
            sl[t] = sl[t] * expf(sm[t] - nm) + l2 * expf(m2 - nm);
            sm[t] = nm;
        }
        __syncthreads();
    }
    if (t == 0) { fm = sm[0]; fl = logf(sl[0]); }
    __syncthreads();
    int i = blockIdx.x * 256 + t;
    if (i < V) out[i] = ws[WS_LOGITS + i] - fm - fl;
}

extern "C" void kernel_launch(void* const* d_in, const int* in_sizes, int n_in,
                              void* d_out, int out_size, void* d_ws, size_t ws_size,
                              hipStream_t stream) {
    const int*   word   = (const int*)d_in[0];
    const float* h0     = (const float*)d_in[1];
    const float* c0     = (const float*)d_in[2];
    const float* enc    = (const float*)d_in[3];
    const float* emb    = (const float*)d_in[4];
    const float* Wih    = (const float*)d_in[5];
    const float* Whh    = (const float*)d_in[6];
    const float* bih    = (const float*)d_in[7];
    const float* bhh    = (const float*)d_in[8];
    const float* attn_W = (const float*)d_in[9];
    const float* attn_b = (const float*)d_in[10];
    const float* outW   = (const float*)d_in[11];
    const float* outb   = (const float*)d_in[12];
    float* out = (float*)d_out;
    float* ws  = (float*)d_ws;

    lstm_kernel<<<H + 9, 256, 0, stream>>>(word, emb, Wih, Whh, bih, bhh, h0, c0, out, ws);
    attnv_kernel<<<128 + GEMV_A_BLOCKS, 256, 0, stream>>>(attn_W, attn_b, out, outW, outb, ws);
    scores_kernel<<<S / 4 + GEMV_S_BLOCKS, 256, 0, stream>>>(enc, outW, outb, ws);
    softmax_kernel<<<1 + GEMV_SM_BLOCKS, 1024, 0, stream>>>(ws, out, outW, outb, ws);
    context_kernel<<<256 + GEMV_C_BLOCKS, 256, 0, stream>>>(enc, out, outW, outb, ws);
    logits_ctx_kernel<<<LCB, 256, 0, stream>>>(outW, ws);
    lsout_kernel<<<(V + 255) / 256, 256, 0, stream>>>(ws, out);
}